// Round 3
// baseline (255.854 us; speedup 1.0000x reference)
//
#include <hip/hip_runtime.h>
#include <math.h>

#define Bc 8
#define Sc 512
#define Hc 512
#define NHc 8
#define HDc 64
#define DISc 32
#define S2c 1024

typedef __attribute__((ext_vector_type(8))) short bf16x8;
typedef __attribute__((ext_vector_type(4))) float f32x4;
#define MFMA16(a, b, c) __builtin_amdgcn_mfma_f32_16x16x32_bf16(a, b, c, 0, 0, 0)

__device__ __forceinline__ unsigned short f2bf(float f) {
  unsigned u = __float_as_uint(f);
  return (unsigned short)((u + 0x7fffu + ((u >> 16) & 1u)) >> 16);  // RNE
}
__device__ __forceinline__ float b2f(unsigned short u) {
  return __uint_as_float((unsigned)u << 16);
}
__device__ __forceinline__ bf16x8 ldb16x8(const unsigned short* p) {
  union { uint4 u; bf16x8 s; } cv;
  cv.u = *(const uint4*)p;
  return cv.s;
}

// ---------------------------------------------------------------------------
// fp32 -> bf16 conversions. Wq is pre-scaled by 0.125 (exact exponent shift)
// so QK^T comes out of the attention MFMA already divided by 8.
// ---------------------------------------------------------------------------
__global__ __launch_bounds__(256) void cvt5_k(
    const float* __restrict__ x, const float* __restrict__ wq,
    const float* __restrict__ wk, const float* __restrict__ wv,
    const float* __restrict__ wo, unsigned short* __restrict__ x16,
    unsigned short* __restrict__ w16q, unsigned short* __restrict__ w16k,
    unsigned short* __restrict__ w16v, unsigned short* __restrict__ w16o) {
  int i = blockIdx.x * 256 + threadIdx.x;
  const float* src; unsigned short* dst; int off; float sc = 1.f;
  if (i < 524288)      { src = x;  dst = x16;  off = i; }
  else if (i < 589824) { src = wq; dst = w16q; off = i - 524288; sc = 0.125f; }
  else if (i < 720896) { src = wk; dst = w16k; off = i - 589824; }
  else if (i < 851968) { src = wv; dst = w16v; off = i - 720896; }
  else                 { src = wo; dst = w16o; off = i - 851968; }
  float4 v = ((const float4*)src)[off];
  ushort4 u;
  u.x = f2bf(v.x * sc); u.y = f2bf(v.y * sc);
  u.z = f2bf(v.z * sc); u.w = f2bf(v.w * sc);
  ((ushort4*)dst)[off] = u;
}

// ---------------------------------------------------------------------------
// Pack rel (int32 0..31) + mask (u8) -> u8 (rd | m<<7).
// ---------------------------------------------------------------------------
__global__ __launch_bounds__(256) void pack_k(const int* __restrict__ rel,
                                              const unsigned char* __restrict__ mask,
                                              unsigned char* __restrict__ pk8) {
  int i = blockIdx.x * 256 + threadIdx.x;
  const int* rp = rel + i * 16;
  uint4 mu = *(const uint4*)(mask + i * 16);
  const unsigned char* mb = (const unsigned char*)&mu;
  uint4 o;
  unsigned* ow = (unsigned*)&o;
#pragma unroll
  for (int g = 0; g < 4; ++g) {
    int4 r4 = ((const int4*)rp)[g];
    unsigned b0 = ((unsigned)r4.x & 31u) | (mb[g * 4 + 0] ? 0x80u : 0u);
    unsigned b1 = ((unsigned)r4.y & 31u) | (mb[g * 4 + 1] ? 0x80u : 0u);
    unsigned b2 = ((unsigned)r4.z & 31u) | (mb[g * 4 + 2] ? 0x80u : 0u);
    unsigned b3 = ((unsigned)r4.w & 31u) | (mb[g * 4 + 3] ? 0x80u : 0u);
    ow[g] = b0 | (b1 << 8) | (b2 << 16) | (b3 << 24);
  }
  *(uint4*)(pk8 + i * 16) = o;
}

// ---------------------------------------------------------------------------
// Fold pos-embeddings into the projection weights (unchanged).
// ---------------------------------------------------------------------------
__global__ __launch_bounds__(256) void wemb_k(
    const float* __restrict__ qpe, const float* __restrict__ kpe,
    const float* __restrict__ Wq, const float* __restrict__ Wk,
    unsigned short* __restrict__ wqp, unsigned short* __restrict__ wkp) {
  const int bid = blockIdx.x;
  const int cc = bid & 3, unit = bid >> 2;
  const int c0 = cc << 7;
  const int t = threadIdx.x;
  const float* emb; const float* Wsrc; unsigned short* outp; int rowbase, h;
  if (unit < 8) {
    h = unit; emb = qpe; Wsrc = Wq + (size_t)(h * 64) * 512; outp = wqp; rowbase = h * 32;
  } else {
    int u = unit - 8; int e = u >> 3; h = u & 7;
    emb = kpe; Wsrc = Wk + (size_t)(e * 512 + h * 64) * 512; outp = wkp;
    rowbase = e * 256 + h * 32;
  }
  __shared__ float es[32][65];
  __shared__ float wsh[64][132];
  {
    int n = t >> 3, d4 = (t & 7) << 3;
    float4 v0 = *(const float4*)(emb + (size_t)n * 512 + h * 64 + d4);
    float4 v1 = *(const float4*)(emb + (size_t)n * 512 + h * 64 + d4 + 4);
    *(float4*)&es[n][d4] = v0;
    *(float4*)&es[n][d4 + 4] = v1;
  }
#pragma unroll
  for (int p = 0; p < 8; ++p) {
    int slot = t + (p << 8);
    int d = slot >> 5, c4 = (slot & 31) << 2;
    *(float4*)&wsh[d][c4] = *(const float4*)(Wsrc + (size_t)d * 512 + c0 + c4);
  }
  __syncthreads();
  const int n = t >> 3, cb = (t & 7) << 4;
  float acc[16] = {};
#pragma unroll
  for (int d = 0; d < 64; ++d) {
    float ev = es[n][d];
    float4 w0 = *(const float4*)&wsh[d][cb];
    float4 w1 = *(const float4*)&wsh[d][cb + 4];
    float4 w2 = *(const float4*)&wsh[d][cb + 8];
    float4 w3 = *(const float4*)&wsh[d][cb + 12];
    acc[0] = fmaf(ev, w0.x, acc[0]);   acc[1] = fmaf(ev, w0.y, acc[1]);
    acc[2] = fmaf(ev, w0.z, acc[2]);   acc[3] = fmaf(ev, w0.w, acc[3]);
    acc[4] = fmaf(ev, w1.x, acc[4]);   acc[5] = fmaf(ev, w1.y, acc[5]);
    acc[6] = fmaf(ev, w1.z, acc[6]);   acc[7] = fmaf(ev, w1.w, acc[7]);
    acc[8] = fmaf(ev, w2.x, acc[8]);   acc[9] = fmaf(ev, w2.y, acc[9]);
    acc[10] = fmaf(ev, w2.z, acc[10]); acc[11] = fmaf(ev, w2.w, acc[11]);
    acc[12] = fmaf(ev, w3.x, acc[12]); acc[13] = fmaf(ev, w3.y, acc[13]);
    acc[14] = fmaf(ev, w3.z, acc[14]); acc[15] = fmaf(ev, w3.w, acc[15]);
  }
  unsigned short* orow = outp + (size_t)(rowbase + n) * 512 + c0 + cb;
#pragma unroll
  for (int j = 0; j < 16; ++j) orow[j] = f2bf(acc[j] * 0.125f);
}

// ===========================================================================
// Merged QKV projection GEMM — round-0 PROVEN inner loop (64x64 tile, BK=64,
// LDS stride 72, register-pipelined staging, 4 blocks/CU), with a 5-segment
// B-concat + per-segment epilogue so Q/QPW/K/KPW/V run as ONE dispatch
// (grid 52x64 = 3328 blocks) instead of three.
// B = concat(w16q[512], wqp[256], w16k[1024], wkp[512], w16v[1024]) rows,
// all [rows][512] bf16 row-major; segment boundaries are multiples of 64.
// ===========================================================================
__global__ __launch_bounds__(256, 4) void gemmqkv_k(
    const unsigned short* __restrict__ A,
    const unsigned short* __restrict__ wq, const unsigned short* __restrict__ wqp,
    const unsigned short* __restrict__ wk, const unsigned short* __restrict__ wkp,
    const unsigned short* __restrict__ wv,
    unsigned short* __restrict__ q16h, unsigned short* __restrict__ qpw16,
    unsigned short* __restrict__ kb16, unsigned short* __restrict__ kpw16,
    unsigned short* __restrict__ vT16) {
  const int t = threadIdx.x;
  const int w = t >> 6, lane = t & 63, ln = lane & 15, qd = lane >> 4;
  const int wm = (w >> 1) << 5, wn = (w & 1) << 5;
  const int m0 = blockIdx.y << 6, n0 = blockIdx.x << 6;
  __shared__ unsigned short As[64 * 72];
  __shared__ unsigned short Bs[64 * 72];
  const unsigned short* Bb;
  if (n0 < 512)        Bb = wq  + (size_t)n0 * 512;
  else if (n0 < 768)   Bb = wqp + (size_t)(n0 - 512) * 512;
  else if (n0 < 1792)  Bb = wk  + (size_t)(n0 - 768) * 512;
  else if (n0 < 2304)  Bb = wkp + (size_t)(n0 - 1792) * 512;
  else                 Bb = wv  + (size_t)(n0 - 2304) * 512;
  const int r0 = t >> 3, c8 = (t & 7) << 3;
  const unsigned short* ga = A + (size_t)(m0 + r0) * 512 + c8;
  const unsigned short* gb = Bb + (size_t)r0 * 512 + c8;
  const size_t half = (size_t)32 * 512;
  uint4 va0 = *(const uint4*)ga, va1 = *(const uint4*)(ga + half);
  uint4 vb0 = *(const uint4*)gb, vb1 = *(const uint4*)(gb + half);
  f32x4 z = {0.f, 0.f, 0.f, 0.f};
  f32x4 acc[2][2] = {{z, z}, {z, z}};
  for (int k0 = 0; k0 < 512; k0 += 64) {
    *(uint4*)&As[r0 * 72 + c8] = va0;
    *(uint4*)&As[(r0 + 32) * 72 + c8] = va1;
    *(uint4*)&Bs[r0 * 72 + c8] = vb0;
    *(uint4*)&Bs[(r0 + 32) * 72 + c8] = vb1;
    __syncthreads();
    if (k0 + 64 < 512) {
      va0 = *(const uint4*)(ga + k0 + 64);
      va1 = *(const uint4*)(ga + half + k0 + 64);
      vb0 = *(const uint4*)(gb + k0 + 64);
      vb1 = *(const uint4*)(gb + half + k0 + 64);
    }
#pragma unroll
    for (int kk = 0; kk < 64; kk += 32) {
      bf16x8 a0 = ldb16x8(&As[(wm + ln) * 72 + kk + qd * 8]);
      bf16x8 a1 = ldb16x8(&As[(wm + 16 + ln) * 72 + kk + qd * 8]);
      bf16x8 b0 = ldb16x8(&Bs[(wn + ln) * 72 + kk + qd * 8]);
      bf16x8 b1 = ldb16x8(&Bs[(wn + 16 + ln) * 72 + kk + qd * 8]);
      acc[0][0] = MFMA16(a0, b0, acc[0][0]);
      acc[0][1] = MFMA16(a0, b1, acc[0][1]);
      acc[1][0] = MFMA16(a1, b0, acc[1][0]);
      acc[1][1] = MFMA16(a1, b1, acc[1][1]);
    }
    __syncthreads();
  }
#pragma unroll
  for (int tm = 0; tm < 2; ++tm)
#pragma unroll
    for (int tn = 0; tn < 2; ++tn)
#pragma unroll
      for (int r = 0; r < 4; ++r) {
        int m = m0 + wm + tm * 16 + qd * 4 + r;
        int n = n0 + wn + tn * 16 + ln;
        unsigned short v16 = f2bf(acc[tm][tn][r]);
        int bb = m >> 9, s = m & 511;
        if (n0 < 512) {
          int hh = (n >> 6) & 7, d = n & 63;
          q16h[((size_t)(bb * 8 + hh) * 512 + s) * 64 + d] = v16;
        } else if (n0 < 768) {
          int n2 = n - 512, hh = n2 >> 5, nn = n2 & 31;
          qpw16[((size_t)(bb * 8 + hh) * 512 + s) * 32 + nn] = v16;
        } else if (n0 < 1792) {
          int n2 = n - 768, e = n2 >> 9, hh = (n2 >> 6) & 7, d = n2 & 63;
          int k2 = 2 * s + e;
          kb16[((size_t)(bb * 8 + hh) * 1024 + k2) * 64 + d] = v16;
        } else if (n0 < 2304) {
          int n2 = n - 1792, e = n2 >> 8, hh = (n2 >> 5) & 7, nn = n2 & 31;
          int k2 = 2 * s + e;
          kpw16[((size_t)(bb * 8 + hh) * 1024 + k2) * 32 + nn] = v16;
        } else {
          int n2 = n - 2304, e = n2 >> 9, hh = (n2 >> 6) & 7, d = n2 & 63;
          int k2 = 2 * s + e;
          vT16[((size_t)(bb * 8 + hh) * 64 + d) * 1024 + k2] = v16;
        }
      }
}

// ---------------------------------------------------------------------------
// Output projection GEMM — round-0 proven structure, MODE-0 only.
// attn16[4096][512] @ w16o^T -> fp32 out. Grid dim3(8, 64).
// ---------------------------------------------------------------------------
__global__ __launch_bounds__(256, 4) void gemmo_k(
    const unsigned short* __restrict__ A, const unsigned short* __restrict__ Bw,
    float* __restrict__ out) {
  const int t = threadIdx.x;
  const int w = t >> 6, lane = t & 63, ln = lane & 15, qd = lane >> 4;
  const int wm = (w >> 1) << 5, wn = (w & 1) << 5;
  const int m0 = blockIdx.y << 6, n0 = blockIdx.x << 6;
  __shared__ unsigned short As[64 * 72];
  __shared__ unsigned short Bs[64 * 72];
  const unsigned short* Bb = Bw + (size_t)n0 * 512;
  const int r0 = t >> 3, c8 = (t & 7) << 3;
  const unsigned short* ga = A + (size_t)(m0 + r0) * 512 + c8;
  const unsigned short* gb = Bb + (size_t)r0 * 512 + c8;
  const size_t half = (size_t)32 * 512;
  uint4 va0 = *(const uint4*)ga, va1 = *(const uint4*)(ga + half);
  uint4 vb0 = *(const uint4*)gb, vb1 = *(const uint4*)(gb + half);
  f32x4 z = {0.f, 0.f, 0.f, 0.f};
  f32x4 acc[2][2] = {{z, z}, {z, z}};
  for (int k0 = 0; k0 < 512; k0 += 64) {
    *(uint4*)&As[r0 * 72 + c8] = va0;
    *(uint4*)&As[(r0 + 32) * 72 + c8] = va1;
    *(uint4*)&Bs[r0 * 72 + c8] = vb0;
    *(uint4*)&Bs[(r0 + 32) * 72 + c8] = vb1;
    __syncthreads();
    if (k0 + 64 < 512) {
      va0 = *(const uint4*)(ga + k0 + 64);
      va1 = *(const uint4*)(ga + half + k0 + 64);
      vb0 = *(const uint4*)(gb + k0 + 64);
      vb1 = *(const uint4*)(gb + half + k0 + 64);
    }
#pragma unroll
    for (int kk = 0; kk < 64; kk += 32) {
      bf16x8 a0 = ldb16x8(&As[(wm + ln) * 72 + kk + qd * 8]);
      bf16x8 a1 = ldb16x8(&As[(wm + 16 + ln) * 72 + kk + qd * 8]);
      bf16x8 b0 = ldb16x8(&Bs[(wn + ln) * 72 + kk + qd * 8]);
      bf16x8 b1 = ldb16x8(&Bs[(wn + 16 + ln) * 72 + kk + qd * 8]);
      acc[0][0] = MFMA16(a0, b0, acc[0][0]);
      acc[0][1] = MFMA16(a0, b1, acc[0][1]);
      acc[1][0] = MFMA16(a1, b0, acc[1][0]);
      acc[1][1] = MFMA16(a1, b1, acc[1][1]);
    }
    __syncthreads();
  }
#pragma unroll
  for (int tm = 0; tm < 2; ++tm)
#pragma unroll
    for (int tn = 0; tn < 2; ++tn)
#pragma unroll
      for (int r = 0; r < 4; ++r) {
        int m = m0 + wm + tm * 16 + qd * 4 + r;
        int n = n0 + wn + tn * 16 + ln;
        out[(size_t)m * 512 + n] = acc[tm][tn][r];
      }
}

// ---------------------------------------------------------------------------
// MFMA attention. This round: LDS diet 60928 -> 52736 B (pbuf 8x16x72 ->
// 8x16x40 via split PV: P is consumed as two independent 32-col A-frags, so
// each half reuses the same per-wave 16x40 buffer) => 3 blocks/CU instead of
// 2 (OccupancyPercent 39 -> ~58). Numerics identical. u64 vdw histogram and
// all lookup strides unchanged.
// ---------------------------------------------------------------------------
__global__ __launch_bounds__(512, 6) void attn6_k(
    const unsigned short* __restrict__ q16h, const unsigned short* __restrict__ kb16,
    const unsigned short* __restrict__ vT16, const unsigned short* __restrict__ qpw16,
    const unsigned short* __restrict__ kpw16, const unsigned char* __restrict__ pk8,
    const float* __restrict__ v_emb, unsigned short* __restrict__ attn16) {
  const int bid = blockIdx.x;
  const int b = bid & 7;                 // XCD-affine: bid%8 == b
  const int h = (bid >> 3) & 7;
  const int qb = ((bid >> 6) & 7) << 6;
  const int t = threadIdx.x;
  const int w = t >> 6;
  const int g = w >> 2;
  const int ws4 = w & 3;
  const int lane = t & 63;
  const int ln = lane & 15;
  const int qd = lane >> 4;

  __shared__ __align__(16) char smem[52736];
  unsigned char*  pkt  = (unsigned char*)smem;                // 2 x (64x80) u8   [0,10240)
  unsigned short* kpws = (unsigned short*)(smem + 10240);     // 2 x (64x36) u16  [10240,19456)
  unsigned short* q32s = (unsigned short*)(smem + 19456);     // 64x36 u16        [19456,24064)
  unsigned short* pbuf = (unsigned short*)(smem + 24064);     // 8 x (16x40) u16  [24064,34304)
  unsigned long long* vdwm64 = (unsigned long long*)(smem + 34304); // 4 x (16x36) u64 [34304,52736)
  // endgame aliases (source regions dead by then):
  float*          accbuf = (float*)smem;                      // 4 x (16x68) f    [0,17408)
  unsigned short* vest   = (unsigned short*)(smem + 19456);   // 64x40 u16        [19456,24576)
  unsigned short* vdwb   = (unsigned short*)(smem + 24576);   // 4 x (16x40) u16  [24576,29696)

  for (int i = t; i < 4 * 16 * 36; i += 512) vdwm64[i] = 0ull;
  if (t < 256) {  // q32s: 64 q x 32 n bf16, straight copy
    int row = t >> 2, c8 = (t & 3) << 3;
    *(uint4*)&q32s[row * 36 + c8] =
        *(const uint4*)(qpw16 + ((size_t)((b * 8 + h) * 512 + qb) + row) * 32 + c8);
  }
  const unsigned short* kbase = kb16 + (size_t)(b * 8 + h) * 65536;
  const unsigned short* vbase = vT16 + (size_t)(b * 8 + h) * 65536;
  bf16x8 aQ[2];
  {
    const unsigned short* qsrc =
        q16h + ((size_t)((b * 8 + h) * 512 + qb + ws4 * 16 + ln)) * 64;
    aQ[0] = ldb16x8(qsrc + qd * 8);
    aQ[1] = ldb16x8(qsrc + 32 + qd * 8);
  }
  f32x4 z = {0.f, 0.f, 0.f, 0.f};
  f32x4 acc[4] = {z, z, z, z};

  // staging addresses (thread-fixed): squad gg = t>>8 stages for kt-half gg
  const int u = t & 255, gg = t >> 8;
  const int qr = u >> 2, cg = (u & 3) << 4;        // pkt slot (bytes)
  const int kc8 = (u & 3) << 3;                    // kpw slot (u16)
  const unsigned char* pks = pk8 + ((size_t)(b * 512 + qb + qr)) * 1024 + (gg << 9);
  const unsigned short* kps =
      kpw16 + ((size_t)((b * 8 + h) * 1024) + (gg << 9) + qr) * 32 + kc8;
  unsigned char* pt_w = pkt + gg * 5120 + qr * 80 + cg;
  unsigned short* kp_w = kpws + gg * 2304 + qr * 36 + kc8;

  uint4 pv = *(const uint4*)(pks + cg);
  uint4 kv = *(const uint4*)kps;

  for (int kti = 0; kti < 8; ++kti) {
    *(uint4*)pt_w = pv;
    *(uint4*)kp_w = kv;
    __syncthreads();
    if (kti < 7) {  // prefetch next kt's staging under the MFMA work
      pv = *(const uint4*)(pks + ((kti + 1) << 6) + cg);
      kv = *(const uint4*)(kps + ((size_t)(kti + 1) << 11));   // (kti+1)*64*32
    }
    const int kt0 = (kti + g * 8) << 6;

    // ---- QK^T: B-frags straight from global (same-XCD L2) ----
    f32x4 sc4[4];
#pragma unroll
    for (int t4 = 0; t4 < 4; ++t4) {
      f32x4 c = z;
      c = MFMA16(aQ[0], ldb16x8(kbase + (size_t)(kt0 + t4 * 16 + ln) * 64 + qd * 8), c);
      c = MFMA16(aQ[1], ldb16x8(kbase + (size_t)(kt0 + t4 * 16 + ln) * 64 + 32 + qd * 8), c);
      sc4[t4] = c;
    }

    // ---- bias + mask + exp; u64 vdw scatter; P -> pbuf; PV in two halves ----
    unsigned char* pt_ = pkt + g * 5120;
    unsigned short* kp_ = kpws + g * 2304;
#pragma unroll
    for (int hf = 0; hf < 2; ++hf) {
#pragma unroll
      for (int r = 0; r < 4; ++r) {
#pragma unroll
        for (int t4h = 0; t4h < 2; ++t4h) {
          int t4 = hf * 2 + t4h;
          int row_l = ws4 * 16 + qd * 4 + r;
          int kl = t4 * 16 + ln;
          unsigned um = pt_[row_l * 80 + kl];
          int rd = um & 31;
          float s = sc4[t4][r] + b2f(q32s[row_l * 36 + rd]) + b2f(kp_[kl * 36 + rd]);
          float p = (um & 0x80u) ? 0.f : __expf(s);
          atomicAdd(&vdwm64[ws4 * 576 + (qd * 4 + r) * 36 + rd],
                    (unsigned long long)(p * 67108864.0f));     // Q = 2^26
          pbuf[w * 640 + (qd * 4 + r) * 40 + t4h * 16 + ln] = f2bf(p);
        }
      }
      // ---- PV half: O += P(16x32) @ V(32x64) ----
      bf16x8 ah = ldb16x8(&pbuf[w * 640 + ln * 40 + qd * 8]);
#pragma unroll
      for (int dt = 0; dt < 4; ++dt)
        acc[dt] = MFMA16(ah, ldb16x8(vbase + (size_t)(dt * 16 + ln) * 1024 + kt0 + hf * 32 + qd * 8), acc[dt]);
    }
    __syncthreads();
  }

  // ---- endgame: vest staged by g0 threads, vdwb built by g1 waves ----
  if (t < 256) {
    int n = t >> 3, d0 = (t & 7) << 3;
    const float* src = v_emb + ((size_t)n << 9) + (h << 6) + d0;
    float4 f0 = *(const float4*)src;
    float4 f1 = *(const float4*)(src + 4);
    vest[(d0 + 0) * 40 + n] = f2bf(f0.x); vest[(d0 + 1) * 40 + n] = f2bf(f0.y);
    vest[(d0 + 2) * 40 + n] = f2bf(f0.z); vest[(d0 + 3) * 40 + n] = f2bf(f0.w);
    vest[(d0 + 4) * 40 + n] = f2bf(f1.x); vest[(d0 + 5) * 40 + n] = f2bf(f1.y);
    vest[(d0 + 6) * 40 + n] = f2bf(f1.z); vest[(d0 + 7) * 40 + n] = f2bf(f1.w);
  } else {
    int row = lane >> 2, n0 = (lane & 3) << 3;
    float vv[8];
#pragma unroll
    for (int j = 0; j < 8; ++j)
      vv[j] = (float)vdwm64[ws4 * 576 + row * 36 + n0 + j] * 1.4901161193847656e-8f;
    ushort4 u0, u1;
    u0.x = f2bf(vv[0]); u0.y = f2bf(vv[1]); u0.z = f2bf(vv[2]); u0.w = f2bf(vv[3]);
    u1.x = f2bf(vv[4]); u1.y = f2bf(vv[5]); u1.z = f2bf(vv[6]); u1.w = f2bf(vv[7]);
    *(ushort4*)&vdwb[ws4 * 640 + row * 40 + n0] = u0;
    *(ushort4*)&vdwb[ws4 * 640 + row * 40 + n0 + 4] = u1;
  }
  __syncthreads();

  if (g == 1) {
    bf16x8 av = ldb16x8(&vdwb[ws4 * 640 + ln * 40 + qd * 8]);
#pragma unroll
    for (int dt = 0; dt < 4; ++dt)
      acc[dt] = MFMA16(av, ldb16x8(&vest[(dt * 16 + ln) * 40 + qd * 8]), acc[dt]);
#pragma unroll
    for (int r = 0; r < 4; ++r)
#pragma unroll
      for (int dt = 0; dt < 4; ++dt)
        accbuf[ws4 * 1088 + (qd * 4 + r) * 68 + dt * 16 + ln] = acc[dt][r];
  }
  __syncthreads();

  if (g == 0) {
    float inv[4];
#pragma unroll
    for (int r = 0; r < 4; ++r) {
      unsigned long long lu = 0ull;
#pragma unroll
      for (int n = 0; n < 32; ++n)
        lu += vdwm64[ws4 * 576 + (qd * 4 + r) * 36 + n];
      inv[r] = 67108864.0f / (float)lu;
    }
    unsigned short* obase =
        attn16 + ((size_t)(b * 512 + qb + ws4 * 16 + qd * 4)) * 512 + (h << 6);
#pragma unroll
    for (int r = 0; r < 4; ++r)
#pragma unroll
      for (int dt = 0; dt < 4; ++dt) {
        float v = (acc[dt][r] + accbuf[ws4 * 1088 + (qd * 4 + r) * 68 + dt * 16 + ln]) * inv[r];
        obase[(size_t)r * 512 + dt * 16 + ln] = f2bf(v);
      }
  }
}

// ---------------------------------------------------------------------------
extern "C" void kernel_launch(void* const* d_in, const int* in_sizes, int n_in,
                              void* d_out, int out_size, void* d_ws, size_t ws_size,
                              hipStream_t stream) {
  const float* x = (const float*)d_in[0];
  const int* rel = (const int*)d_in[1];
  const unsigned char* mask = (const unsigned char*)d_in[2];
  const float* qpe = (const float*)d_in[3];
  const float* kpe = (const float*)d_in[4];
  const float* vpe = (const float*)d_in[5];
  const float* Wq = (const float*)d_in[6];
  const float* Wk = (const float*)d_in[7];
  const float* Wv = (const float*)d_in[8];
  const float* Wo = (const float*)d_in[9];
  float* out = (float*)d_out;

  unsigned short* u = (unsigned short*)d_ws;
  unsigned short* x16    = u;                    // 2,097,152
  unsigned short* w16q   = x16 + 2097152;        //   262,144
  unsigned short* w16k   = w16q + 262144;        //   524,288
  unsigned short* w16v   = w16k + 524288;        //   524,288
  unsigned short* w16o   = w16v + 524288;        //   262,144
  unsigned short* wqp16  = w16o + 262144;        //   131,072  (256x512)
  unsigned short* wkp16  = wqp16 + 131072;       //   262,144  (512x512)
  unsigned short* q16h   = wkp16 + 262144;       // 2,097,152
  unsigned short* qpw16  = q16h + 2097152;       // 1,048,576  [b,h,s,32]
  unsigned short* kb16   = qpw16 + 1048576;      // 4,194,304
  unsigned short* kpw16  = kb16 + 4194304;       // 2,097,152  [b,h,k2,32]
  unsigned short* vT16   = kpw16 + 2097152;      // 4,194,304
  unsigned short* attn16 = vT16 + 4194304;       // 2,097,152
  unsigned char* pk8 = (unsigned char*)(attn16 + 2097152);  // 4 MB  -> ~44 MB total

  pack_k<<<1024, 256, 0, stream>>>(rel, mask, pk8);
  cvt5_k<<<3584, 256, 0, stream>>>(x, Wq, Wk, Wv, Wo, x16, w16q, w16k, w16v, w16o);
  wemb_k<<<96, 256, 0, stream>>>(qpe, kpe, Wq, Wk, wqp16, wkp16);
  gemmqkv_k<<<dim3(52, 64), 256, 0, stream>>>(x16, w16q, wqp16, w16k, wkp16, w16v,
                                              q16h, qpw16, kb16, kpw16, vT16);
  attn6_k<<<512, 512, 0, stream>>>(q16h, kb16, vT16, qpw16, kpw16, pk8, vpe, attn16);
  gemmo_k<<<dim3(8, 64), 256, 0, stream>>>(attn16, w16o, out);
}

// Round 4
// 216.511 us; speedup vs baseline: 1.1817x; 1.1817x over previous
//
#include <hip/hip_runtime.h>
#include <math.h>

#define Bc 8
#define Sc 512
#define Hc 512
#define NHc 8
#define HDc 64
#define DISc 32
#define S2c 1024

typedef __attribute__((ext_vector_type(8))) short bf16x8;
typedef __attribute__((ext_vector_type(4))) float f32x4;
#define MFMA16(a, b, c) __builtin_amdgcn_mfma_f32_16x16x32_bf16(a, b, c, 0, 0, 0)

__device__ __forceinline__ unsigned short f2bf(float f) {
  unsigned u = __float_as_uint(f);
  return (unsigned short)((u + 0x7fffu + ((u >> 16) & 1u)) >> 16);  // RNE
}
__device__ __forceinline__ float b2f(unsigned short u) {
  return __uint_as_float((unsigned)u << 16);
}
__device__ __forceinline__ bf16x8 ldb16x8(const unsigned short* p) {
  union { uint4 u; bf16x8 s; } cv;
  cv.u = *(const uint4*)p;
  return cv.s;
}

// ---------------------------------------------------------------------------
// fp32 -> bf16 conversions. Wq is pre-scaled by 0.125 (exact exponent shift)
// so QK^T comes out of the attention MFMA already divided by 8.
// ---------------------------------------------------------------------------
__global__ __launch_bounds__(256) void cvt5_k(
    const float* __restrict__ x, const float* __restrict__ wq,
    const float* __restrict__ wk, const float* __restrict__ wv,
    const float* __restrict__ wo, unsigned short* __restrict__ x16,
    unsigned short* __restrict__ w16q, unsigned short* __restrict__ w16k,
    unsigned short* __restrict__ w16v, unsigned short* __restrict__ w16o) {
  int i = blockIdx.x * 256 + threadIdx.x;
  const float* src; unsigned short* dst; int off; float sc = 1.f;
  if (i < 524288)      { src = x;  dst = x16;  off = i; }
  else if (i < 589824) { src = wq; dst = w16q; off = i - 524288; sc = 0.125f; }
  else if (i < 720896) { src = wk; dst = w16k; off = i - 589824; }
  else if (i < 851968) { src = wv; dst = w16v; off = i - 720896; }
  else                 { src = wo; dst = w16o; off = i - 851968; }
  float4 v = ((const float4*)src)[off];
  ushort4 u;
  u.x = f2bf(v.x * sc); u.y = f2bf(v.y * sc);
  u.z = f2bf(v.z * sc); u.w = f2bf(v.w * sc);
  ((ushort4*)dst)[off] = u;
}

// ---------------------------------------------------------------------------
// Pack rel (int32 0..31) + mask (u8) -> u8 (rd | m<<7).
// ---------------------------------------------------------------------------
__global__ __launch_bounds__(256) void pack_k(const int* __restrict__ rel,
                                              const unsigned char* __restrict__ mask,
                                              unsigned char* __restrict__ pk8) {
  int i = blockIdx.x * 256 + threadIdx.x;
  const int* rp = rel + i * 16;
  uint4 mu = *(const uint4*)(mask + i * 16);
  const unsigned char* mb = (const unsigned char*)&mu;
  uint4 o;
  unsigned* ow = (unsigned*)&o;
#pragma unroll
  for (int g = 0; g < 4; ++g) {
    int4 r4 = ((const int4*)rp)[g];
    unsigned b0 = ((unsigned)r4.x & 31u) | (mb[g * 4 + 0] ? 0x80u : 0u);
    unsigned b1 = ((unsigned)r4.y & 31u) | (mb[g * 4 + 1] ? 0x80u : 0u);
    unsigned b2 = ((unsigned)r4.z & 31u) | (mb[g * 4 + 2] ? 0x80u : 0u);
    unsigned b3 = ((unsigned)r4.w & 31u) | (mb[g * 4 + 3] ? 0x80u : 0u);
    ow[g] = b0 | (b1 << 8) | (b2 << 16) | (b3 << 24);
  }
  *(uint4*)(pk8 + i * 16) = o;
}

// ---------------------------------------------------------------------------
// Fold pos-embeddings into the projection weights (unchanged).
// ---------------------------------------------------------------------------
__global__ __launch_bounds__(256) void wemb_k(
    const float* __restrict__ qpe, const float* __restrict__ kpe,
    const float* __restrict__ Wq, const float* __restrict__ Wk,
    unsigned short* __restrict__ wqp, unsigned short* __restrict__ wkp) {
  const int bid = blockIdx.x;
  const int cc = bid & 3, unit = bid >> 2;
  const int c0 = cc << 7;
  const int t = threadIdx.x;
  const float* emb; const float* Wsrc; unsigned short* outp; int rowbase, h;
  if (unit < 8) {
    h = unit; emb = qpe; Wsrc = Wq + (size_t)(h * 64) * 512; outp = wqp; rowbase = h * 32;
  } else {
    int u = unit - 8; int e = u >> 3; h = u & 7;
    emb = kpe; Wsrc = Wk + (size_t)(e * 512 + h * 64) * 512; outp = wkp;
    rowbase = e * 256 + h * 32;
  }
  __shared__ float es[32][65];
  __shared__ float wsh[64][132];
  {
    int n = t >> 3, d4 = (t & 7) << 3;
    float4 v0 = *(const float4*)(emb + (size_t)n * 512 + h * 64 + d4);
    float4 v1 = *(const float4*)(emb + (size_t)n * 512 + h * 64 + d4 + 4);
    *(float4*)&es[n][d4] = v0;
    *(float4*)&es[n][d4 + 4] = v1;
  }
#pragma unroll
  for (int p = 0; p < 8; ++p) {
    int slot = t + (p << 8);
    int d = slot >> 5, c4 = (slot & 31) << 2;
    *(float4*)&wsh[d][c4] = *(const float4*)(Wsrc + (size_t)d * 512 + c0 + c4);
  }
  __syncthreads();
  const int n = t >> 3, cb = (t & 7) << 4;
  float acc[16] = {};
#pragma unroll
  for (int d = 0; d < 64; ++d) {
    float ev = es[n][d];
    float4 w0 = *(const float4*)&wsh[d][cb];
    float4 w1 = *(const float4*)&wsh[d][cb + 4];
    float4 w2 = *(const float4*)&wsh[d][cb + 8];
    float4 w3 = *(const float4*)&wsh[d][cb + 12];
    acc[0] = fmaf(ev, w0.x, acc[0]);   acc[1] = fmaf(ev, w0.y, acc[1]);
    acc[2] = fmaf(ev, w0.z, acc[2]);   acc[3] = fmaf(ev, w0.w, acc[3]);
    acc[4] = fmaf(ev, w1.x, acc[4]);   acc[5] = fmaf(ev, w1.y, acc[5]);
    acc[6] = fmaf(ev, w1.z, acc[6]);   acc[7] = fmaf(ev, w1.w, acc[7]);
    acc[8] = fmaf(ev, w2.x, acc[8]);   acc[9] = fmaf(ev, w2.y, acc[9]);
    acc[10] = fmaf(ev, w2.z, acc[10]); acc[11] = fmaf(ev, w2.w, acc[11]);
    acc[12] = fmaf(ev, w3.x, acc[12]); acc[13] = fmaf(ev, w3.y, acc[13]);
    acc[14] = fmaf(ev, w3.z, acc[14]); acc[15] = fmaf(ev, w3.w, acc[15]);
  }
  unsigned short* orow = outp + (size_t)(rowbase + n) * 512 + c0 + cb;
#pragma unroll
  for (int j = 0; j < 16; ++j) orow[j] = f2bf(acc[j] * 0.125f);
}

// ===========================================================================
// Merged QKV projection GEMM — round-0 PROVEN inner loop (64x64 tile, BK=64,
// LDS stride 72, register-pipelined staging, 4 blocks/CU), with a 5-segment
// B-concat + per-segment epilogue so Q/QPW/K/KPW/V run as ONE dispatch
// (grid 52x64 = 3328 blocks). Measured round 3: non-attn total 143 us vs 155
// for the split version — keep.
// ===========================================================================
__global__ __launch_bounds__(256, 4) void gemmqkv_k(
    const unsigned short* __restrict__ A,
    const unsigned short* __restrict__ wq, const unsigned short* __restrict__ wqp,
    const unsigned short* __restrict__ wk, const unsigned short* __restrict__ wkp,
    const unsigned short* __restrict__ wv,
    unsigned short* __restrict__ q16h, unsigned short* __restrict__ qpw16,
    unsigned short* __restrict__ kb16, unsigned short* __restrict__ kpw16,
    unsigned short* __restrict__ vT16) {
  const int t = threadIdx.x;
  const int w = t >> 6, lane = t & 63, ln = lane & 15, qd = lane >> 4;
  const int wm = (w >> 1) << 5, wn = (w & 1) << 5;
  const int m0 = blockIdx.y << 6, n0 = blockIdx.x << 6;
  __shared__ unsigned short As[64 * 72];
  __shared__ unsigned short Bs[64 * 72];
  const unsigned short* Bb;
  if (n0 < 512)        Bb = wq  + (size_t)n0 * 512;
  else if (n0 < 768)   Bb = wqp + (size_t)(n0 - 512) * 512;
  else if (n0 < 1792)  Bb = wk  + (size_t)(n0 - 768) * 512;
  else if (n0 < 2304)  Bb = wkp + (size_t)(n0 - 1792) * 512;
  else                 Bb = wv  + (size_t)(n0 - 2304) * 512;
  const int r0 = t >> 3, c8 = (t & 7) << 3;
  const unsigned short* ga = A + (size_t)(m0 + r0) * 512 + c8;
  const unsigned short* gb = Bb + (size_t)r0 * 512 + c8;
  const size_t half = (size_t)32 * 512;
  uint4 va0 = *(const uint4*)ga, va1 = *(const uint4*)(ga + half);
  uint4 vb0 = *(const uint4*)gb, vb1 = *(const uint4*)(gb + half);
  f32x4 z = {0.f, 0.f, 0.f, 0.f};
  f32x4 acc[2][2] = {{z, z}, {z, z}};
  for (int k0 = 0; k0 < 512; k0 += 64) {
    *(uint4*)&As[r0 * 72 + c8] = va0;
    *(uint4*)&As[(r0 + 32) * 72 + c8] = va1;
    *(uint4*)&Bs[r0 * 72 + c8] = vb0;
    *(uint4*)&Bs[(r0 + 32) * 72 + c8] = vb1;
    __syncthreads();
    if (k0 + 64 < 512) {
      va0 = *(const uint4*)(ga + k0 + 64);
      va1 = *(const uint4*)(ga + half + k0 + 64);
      vb0 = *(const uint4*)(gb + k0 + 64);
      vb1 = *(const uint4*)(gb + half + k0 + 64);
    }
#pragma unroll
    for (int kk = 0; kk < 64; kk += 32) {
      bf16x8 a0 = ldb16x8(&As[(wm + ln) * 72 + kk + qd * 8]);
      bf16x8 a1 = ldb16x8(&As[(wm + 16 + ln) * 72 + kk + qd * 8]);
      bf16x8 b0 = ldb16x8(&Bs[(wn + ln) * 72 + kk + qd * 8]);
      bf16x8 b1 = ldb16x8(&Bs[(wn + 16 + ln) * 72 + kk + qd * 8]);
      acc[0][0] = MFMA16(a0, b0, acc[0][0]);
      acc[0][1] = MFMA16(a0, b1, acc[0][1]);
      acc[1][0] = MFMA16(a1, b0, acc[1][0]);
      acc[1][1] = MFMA16(a1, b1, acc[1][1]);
    }
    __syncthreads();
  }
#pragma unroll
  for (int tm = 0; tm < 2; ++tm)
#pragma unroll
    for (int tn = 0; tn < 2; ++tn)
#pragma unroll
      for (int r = 0; r < 4; ++r) {
        int m = m0 + wm + tm * 16 + qd * 4 + r;
        int n = n0 + wn + tn * 16 + ln;
        unsigned short v16 = f2bf(acc[tm][tn][r]);
        int bb = m >> 9, s = m & 511;
        if (n0 < 512) {
          int hh = (n >> 6) & 7, d = n & 63;
          q16h[((size_t)(bb * 8 + hh) * 512 + s) * 64 + d] = v16;
        } else if (n0 < 768) {
          int n2 = n - 512, hh = n2 >> 5, nn = n2 & 31;
          qpw16[((size_t)(bb * 8 + hh) * 512 + s) * 32 + nn] = v16;
        } else if (n0 < 1792) {
          int n2 = n - 768, e = n2 >> 9, hh = (n2 >> 6) & 7, d = n2 & 63;
          int k2 = 2 * s + e;
          kb16[((size_t)(bb * 8 + hh) * 1024 + k2) * 64 + d] = v16;
        } else if (n0 < 2304) {
          int n2 = n - 1792, e = n2 >> 8, hh = (n2 >> 5) & 7, nn = n2 & 31;
          int k2 = 2 * s + e;
          kpw16[((size_t)(bb * 8 + hh) * 1024 + k2) * 32 + nn] = v16;
        } else {
          int n2 = n - 2304, e = n2 >> 9, hh = (n2 >> 6) & 7, d = n2 & 63;
          int k2 = 2 * s + e;
          vT16[((size_t)(bb * 8 + hh) * 64 + d) * 1024 + k2] = v16;
        }
      }
}

// ---------------------------------------------------------------------------
// Output projection GEMM — round-0 proven structure, MODE-0 only.
// attn16[4096][512] @ w16o^T -> fp32 out. Grid dim3(8, 64).
// ---------------------------------------------------------------------------
__global__ __launch_bounds__(256, 4) void gemmo_k(
    const unsigned short* __restrict__ A, const unsigned short* __restrict__ Bw,
    float* __restrict__ out) {
  const int t = threadIdx.x;
  const int w = t >> 6, lane = t & 63, ln = lane & 15, qd = lane >> 4;
  const int wm = (w >> 1) << 5, wn = (w & 1) << 5;
  const int m0 = blockIdx.y << 6, n0 = blockIdx.x << 6;
  __shared__ unsigned short As[64 * 72];
  __shared__ unsigned short Bs[64 * 72];
  const unsigned short* Bb = Bw + (size_t)n0 * 512;
  const int r0 = t >> 3, c8 = (t & 7) << 3;
  const unsigned short* ga = A + (size_t)(m0 + r0) * 512 + c8;
  const unsigned short* gb = Bb + (size_t)r0 * 512 + c8;
  const size_t half = (size_t)32 * 512;
  uint4 va0 = *(const uint4*)ga, va1 = *(const uint4*)(ga + half);
  uint4 vb0 = *(const uint4*)gb, vb1 = *(const uint4*)(gb + half);
  f32x4 z = {0.f, 0.f, 0.f, 0.f};
  f32x4 acc[2][2] = {{z, z}, {z, z}};
  for (int k0 = 0; k0 < 512; k0 += 64) {
    *(uint4*)&As[r0 * 72 + c8] = va0;
    *(uint4*)&As[(r0 + 32) * 72 + c8] = va1;
    *(uint4*)&Bs[r0 * 72 + c8] = vb0;
    *(uint4*)&Bs[(r0 + 32) * 72 + c8] = vb1;
    __syncthreads();
    if (k0 + 64 < 512) {
      va0 = *(const uint4*)(ga + k0 + 64);
      va1 = *(const uint4*)(ga + half + k0 + 64);
      vb0 = *(const uint4*)(gb + k0 + 64);
      vb1 = *(const uint4*)(gb + half + k0 + 64);
    }
#pragma unroll
    for (int kk = 0; kk < 64; kk += 32) {
      bf16x8 a0 = ldb16x8(&As[(wm + ln) * 72 + kk + qd * 8]);
      bf16x8 a1 = ldb16x8(&As[(wm + 16 + ln) * 72 + kk + qd * 8]);
      bf16x8 b0 = ldb16x8(&Bs[(wn + ln) * 72 + kk + qd * 8]);
      bf16x8 b1 = ldb16x8(&Bs[(wn + 16 + ln) * 72 + kk + qd * 8]);
      acc[0][0] = MFMA16(a0, b0, acc[0][0]);
      acc[0][1] = MFMA16(a0, b1, acc[0][1]);
      acc[1][0] = MFMA16(a1, b0, acc[1][0]);
      acc[1][1] = MFMA16(a1, b1, acc[1][1]);
    }
    __syncthreads();
  }
#pragma unroll
  for (int tm = 0; tm < 2; ++tm)
#pragma unroll
    for (int tn = 0; tn < 2; ++tn)
#pragma unroll
      for (int r = 0; r < 4; ++r) {
        int m = m0 + wm + tm * 16 + qd * 4 + r;
        int n = n0 + wn + tn * 16 + ln;
        out[(size_t)m * 512 + n] = acc[tm][tn][r];
      }
}

// ---------------------------------------------------------------------------
// MFMA attention. LDS diet kept (52736 B -> 3 blocks/CU by LDS); launch
// bound reverted to (512,4): round 3's (512,6) squeezed the VGPR cap and
// spilled to scratch (WRITE_SIZE 4->90 MB, dur 74->113 us). At ~60 VGPR,
// 6 waves/SIMD fit naturally (360 <= 512 regs) -> 3 blocks resident with
// no allocator coercion.
// ---------------------------------------------------------------------------
__global__ __launch_bounds__(512, 4) void attn6_k(
    const unsigned short* __restrict__ q16h, const unsigned short* __restrict__ kb16,
    const unsigned short* __restrict__ vT16, const unsigned short* __restrict__ qpw16,
    const unsigned short* __restrict__ kpw16, const unsigned char* __restrict__ pk8,
    const float* __restrict__ v_emb, unsigned short* __restrict__ attn16) {
  const int bid = blockIdx.x;
  const int b = bid & 7;                 // XCD-affine: bid%8 == b
  const int h = (bid >> 3) & 7;
  const int qb = ((bid >> 6) & 7) << 6;
  const int t = threadIdx.x;
  const int w = t >> 6;
  const int g = w >> 2;
  const int ws4 = w & 3;
  const int lane = t & 63;
  const int ln = lane & 15;
  const int qd = lane >> 4;

  __shared__ __align__(16) char smem[52736];
  unsigned char*  pkt  = (unsigned char*)smem;                // 2 x (64x80) u8   [0,10240)
  unsigned short* kpws = (unsigned short*)(smem + 10240);     // 2 x (64x36) u16  [10240,19456)
  unsigned short* q32s = (unsigned short*)(smem + 19456);     // 64x36 u16        [19456,24064)
  unsigned short* pbuf = (unsigned short*)(smem + 24064);     // 8 x (16x40) u16  [24064,34304)
  unsigned long long* vdwm64 = (unsigned long long*)(smem + 34304); // 4 x (16x36) u64 [34304,52736)
  // endgame aliases (source regions dead by then):
  float*          accbuf = (float*)smem;                      // 4 x (16x68) f    [0,17408)
  unsigned short* vest   = (unsigned short*)(smem + 19456);   // 64x40 u16        [19456,24576)
  unsigned short* vdwb   = (unsigned short*)(smem + 24576);   // 4 x (16x40) u16  [24576,29696)

  for (int i = t; i < 4 * 16 * 36; i += 512) vdwm64[i] = 0ull;
  if (t < 256) {  // q32s: 64 q x 32 n bf16, straight copy
    int row = t >> 2, c8 = (t & 3) << 3;
    *(uint4*)&q32s[row * 36 + c8] =
        *(const uint4*)(qpw16 + ((size_t)((b * 8 + h) * 512 + qb) + row) * 32 + c8);
  }
  const unsigned short* kbase = kb16 + (size_t)(b * 8 + h) * 65536;
  const unsigned short* vbase = vT16 + (size_t)(b * 8 + h) * 65536;
  bf16x8 aQ[2];
  {
    const unsigned short* qsrc =
        q16h + ((size_t)((b * 8 + h) * 512 + qb + ws4 * 16 + ln)) * 64;
    aQ[0] = ldb16x8(qsrc + qd * 8);
    aQ[1] = ldb16x8(qsrc + 32 + qd * 8);
  }
  f32x4 z = {0.f, 0.f, 0.f, 0.f};
  f32x4 acc[4] = {z, z, z, z};

  // staging addresses (thread-fixed): squad gg = t>>8 stages for kt-half gg
  const int u = t & 255, gg = t >> 8;
  const int qr = u >> 2, cg = (u & 3) << 4;        // pkt slot (bytes)
  const int kc8 = (u & 3) << 3;                    // kpw slot (u16)
  const unsigned char* pks = pk8 + ((size_t)(b * 512 + qb + qr)) * 1024 + (gg << 9);
  const unsigned short* kps =
      kpw16 + ((size_t)((b * 8 + h) * 1024) + (gg << 9) + qr) * 32 + kc8;
  unsigned char* pt_w = pkt + gg * 5120 + qr * 80 + cg;
  unsigned short* kp_w = kpws + gg * 2304 + qr * 36 + kc8;

  uint4 pv = *(const uint4*)(pks + cg);
  uint4 kv = *(const uint4*)kps;

  for (int kti = 0; kti < 8; ++kti) {
    *(uint4*)pt_w = pv;
    *(uint4*)kp_w = kv;
    __syncthreads();
    if (kti < 7) {  // prefetch next kt's staging under the MFMA work
      pv = *(const uint4*)(pks + ((kti + 1) << 6) + cg);
      kv = *(const uint4*)(kps + ((size_t)(kti + 1) << 11));   // (kti+1)*64*32
    }
    const int kt0 = (kti + g * 8) << 6;

    // ---- QK^T: B-frags straight from global (same-XCD L2) ----
    f32x4 sc4[4];
#pragma unroll
    for (int t4 = 0; t4 < 4; ++t4) {
      f32x4 c = z;
      c = MFMA16(aQ[0], ldb16x8(kbase + (size_t)(kt0 + t4 * 16 + ln) * 64 + qd * 8), c);
      c = MFMA16(aQ[1], ldb16x8(kbase + (size_t)(kt0 + t4 * 16 + ln) * 64 + 32 + qd * 8), c);
      sc4[t4] = c;
    }

    // ---- bias + mask + exp; u64 vdw scatter; P -> pbuf; PV in two halves ----
    unsigned char* pt_ = pkt + g * 5120;
    unsigned short* kp_ = kpws + g * 2304;
#pragma unroll
    for (int hf = 0; hf < 2; ++hf) {
#pragma unroll
      for (int r = 0; r < 4; ++r) {
#pragma unroll
        for (int t4h = 0; t4h < 2; ++t4h) {
          int t4 = hf * 2 + t4h;
          int row_l = ws4 * 16 + qd * 4 + r;
          int kl = t4 * 16 + ln;
          unsigned um = pt_[row_l * 80 + kl];
          int rd = um & 31;
          float s = sc4[t4][r] + b2f(q32s[row_l * 36 + rd]) + b2f(kp_[kl * 36 + rd]);
          float p = (um & 0x80u) ? 0.f : __expf(s);
          atomicAdd(&vdwm64[ws4 * 576 + (qd * 4 + r) * 36 + rd],
                    (unsigned long long)(p * 67108864.0f));     // Q = 2^26
          pbuf[w * 640 + (qd * 4 + r) * 40 + t4h * 16 + ln] = f2bf(p);
        }
      }
      // ---- PV half: O += P(16x32) @ V(32x64) ----
      bf16x8 ah = ldb16x8(&pbuf[w * 640 + ln * 40 + qd * 8]);
#pragma unroll
      for (int dt = 0; dt < 4; ++dt)
        acc[dt] = MFMA16(ah, ldb16x8(vbase + (size_t)(dt * 16 + ln) * 1024 + kt0 + hf * 32 + qd * 8), acc[dt]);
    }
    __syncthreads();
  }

  // ---- endgame: vest staged by g0 threads, vdwb built by g1 waves ----
  if (t < 256) {
    int n = t >> 3, d0 = (t & 7) << 3;
    const float* src = v_emb + ((size_t)n << 9) + (h << 6) + d0;
    float4 f0 = *(const float4*)src;
    float4 f1 = *(const float4*)(src + 4);
    vest[(d0 + 0) * 40 + n] = f2bf(f0.x); vest[(d0 + 1) * 40 + n] = f2bf(f0.y);
    vest[(d0 + 2) * 40 + n] = f2bf(f0.z); vest[(d0 + 3) * 40 + n] = f2bf(f0.w);
    vest[(d0 + 4) * 40 + n] = f2bf(f1.x); vest[(d0 + 5) * 40 + n] = f2bf(f1.y);
    vest[(d0 + 6) * 40 + n] = f2bf(f1.z); vest[(d0 + 7) * 40 + n] = f2bf(f1.w);
  } else {
    int row = lane >> 2, n0 = (lane & 3) << 3;
    float vv[8];
#pragma unroll
    for (int j = 0; j < 8; ++j)
      vv[j] = (float)vdwm64[ws4 * 576 + row * 36 + n0 + j] * 1.4901161193847656e-8f;
    ushort4 u0, u1;
    u0.x = f2bf(vv[0]); u0.y = f2bf(vv[1]); u0.z = f2bf(vv[2]); u0.w = f2bf(vv[3]);
    u1.x = f2bf(vv[4]); u1.y = f2bf(vv[5]); u1.z = f2bf(vv[6]); u1.w = f2bf(vv[7]);
    *(ushort4*)&vdwb[ws4 * 640 + row * 40 + n0] = u0;
    *(ushort4*)&vdwb[ws4 * 640 + row * 40 + n0 + 4] = u1;
  }
  __syncthreads();

  if (g == 1) {
    bf16x8 av = ldb16x8(&vdwb[ws4 * 640 + ln * 40 + qd * 8]);
#pragma unroll
    for (int dt = 0; dt < 4; ++dt)
      acc[dt] = MFMA16(av, ldb16x8(&vest[(dt * 16 + ln) * 40 + qd * 8]), acc[dt]);
#pragma unroll
    for (int r = 0; r < 4; ++r)
#pragma unroll
      for (int dt = 0; dt < 4; ++dt)
        accbuf[ws4 * 1088 + (qd * 4 + r) * 68 + dt * 16 + ln] = acc[dt][r];
  }
  __syncthreads();

  if (g == 0) {
    float inv[4];
#pragma unroll
    for (int r = 0; r < 4; ++r) {
      unsigned long long lu = 0ull;
#pragma unroll
      for (int n = 0; n < 32; ++n)
        lu += vdwm64[ws4 * 576 + (qd * 4 + r) * 36 + n];
      inv[r] = 67108864.0f / (float)lu;
    }
    unsigned short* obase =
        attn16 + ((size_t)(b * 512 + qb + ws4 * 16 + qd * 4)) * 512 + (h << 6);
#pragma unroll
    for (int r = 0; r < 4; ++r)
#pragma unroll
      for (int dt = 0; dt < 4; ++dt) {
        float v = (acc[dt][r] + accbuf[ws4 * 1088 + (qd * 4 + r) * 68 + dt * 16 + ln]) * inv[r];
        obase[(size_t)r * 512 + dt * 16 + ln] = f2bf(v);
      }
  }
}

// ---------------------------------------------------------------------------
extern "C" void kernel_launch(void* const* d_in, const int* in_sizes, int n_in,
                              void* d_out, int out_size, void* d_ws, size_t ws_size,
                              hipStream_t stream) {
  const float* x = (const float*)d_in[0];
  const int* rel = (const int*)d_in[1];
  const unsigned char* mask = (const unsigned char*)d_in[2];
  const float* qpe = (const float*)d_in[3];
  const float* kpe = (const float*)d_in[4];
  const float* vpe = (const float*)d_in[5];
  const float* Wq = (const float*)d_in[6];
  const float* Wk = (const float*)d_in[7];
  const float* Wv = (const float*)d_in[8];
  const float* Wo = (const float*)d_in[9];
  float* out = (float*)d_out;

  unsigned short* u = (unsigned short*)d_ws;
  unsigned short* x16    = u;                    // 2,097,152
  unsigned short* w16q   = x16 + 2097152;        //   262,144
  unsigned short* w16k   = w16q + 262144;        //   524,288
  unsigned short* w16v   = w16k + 524288;        //   524,288
  unsigned short* w16o   = w16v + 524288;        //   262,144
  unsigned short* wqp16  = w16o + 262144;        //   131,072  (256x512)
  unsigned short* wkp16  = wqp16 + 131072;       //   262,144  (512x512)
  unsigned short* q16h   = wkp16 + 262144;       // 2,097,152
  unsigned short* qpw16  = q16h + 2097152;       // 1,048,576  [b,h,s,32]
  unsigned short* kb16   = qpw16 + 1048576;      // 4,194,304
  unsigned short* kpw16  = kb16 + 4194304;       // 2,097,152  [b,h,k2,32]
  unsigned short* vT16   = kpw16 + 2097152;      // 4,194,304
  unsigned short* attn16 = vT16 + 4194304;       // 2,097,152
  unsigned char* pk8 = (unsigned char*)(attn16 + 2097152);  // 4 MB  -> ~44 MB total

  pack_k<<<1024, 256, 0, stream>>>(rel, mask, pk8);
  cvt5_k<<<3584, 256, 0, stream>>>(x, Wq, Wk, Wv, Wo, x16, w16q, w16k, w16v, w16o);
  wemb_k<<<96, 256, 0, stream>>>(qpe, kpe, Wq, Wk, wqp16, wkp16);
  gemmqkv_k<<<dim3(52, 64), 256, 0, stream>>>(x16, w16q, wqp16, w16k, wkp16, w16v,
                                              q16h, qpw16, kb16, kpw16, vT16);
  attn6_k<<<512, 512, 0, stream>>>(q16h, kb16, vT16, qpw16, kpw16, pk8, vpe, attn16);
  gemmo_k<<<dim3(8, 64), 256, 0, stream>>>(attn16, w16o, out);
}